// Round 7
// baseline (2770.071 us; speedup 1.0000x reference)
//
#include <hip/hip_runtime.h>

// LSTM B=1024 T=512 H=256 (input_size=1, output_size=1) on MI355X.
// R11: kill the barrier. R4/R10 post-mortem: per-step wall 7300-8400cy vs
// ~3500cy busy pipes -> 60% idle at the 2-waves/SIMD ceiling (weights =
// 512KB = whole CU RF; >2 waves/SIMD unreachable, proven R5/R8/R9). The
// idle source hypothesized: all 8 waves share ONE barrier domain ->
// phase-locked; SIMD siblings stall together (barrier drain, h-read chain,
// gate phase). Fix: NO __syncthreads in the loop; per-producer LDS epoch
// flags. Re-tile: wave w owns cols [32w,32w+32) == K-chunk kc=w. kc-loop
// rotated: rk=(w+idx)&7 starts with OWN chunk (zero wait); SIMD siblings
// (w,w+4) are 4 phases apart -> anti-aligned stalls. Weights stored
// PRE-ROTATED by idx so all register indices are compile-time (rule #20).
// Sync: h-writes -> lgkmcnt(0) -> lane0 flag[w]=t+1; readers poll
// flags[rk]>=t (volatile; per-wave DS ordering makes data visible).
// hbuf triple-buffered; skew<=1: during step t a wave polls ALL producers
// >=t before writing slot (t+1)%3, so old readers of that slot are done.
// Per-wave resources (R4's proven split, re-tiled): i,f reg-resident
// (128 regs, pre-rotated), g in LDS (2 of 16 tiles = 128KB), o streamed
// from L2 via 2 rotating quarter-buffers (32 regs), gate consts in 16
// regs (fixes R10's cpk bank conflicts). ~230 V+A regs -> 2 waves/SIMD.

#define HID 256
#define TT 512
#define NBLK 64
#define THREADS 512
#define HPAD 264   // 256 cols + 8 pad (ushort units)

typedef float v4f __attribute__((ext_vector_type(4)));
typedef unsigned int v4u __attribute__((ext_vector_type(4)));
typedef __bf16 v8bf __attribute__((ext_vector_type(8)));

__device__ __forceinline__ unsigned short f2bf(float f) {
    unsigned int u = __builtin_bit_cast(unsigned int, f);
    u += 0x7fffu + ((u >> 16) & 1u);   // RNE
    return (unsigned short)(u >> 16);
}
__device__ __forceinline__ float bf2f(unsigned short s) {
    unsigned int u = ((unsigned int)s) << 16;
    return __builtin_bit_cast(float, u);
}
__device__ __forceinline__ float fsigmoid(float x) {
    float e = exp2f(x * -1.44269504f);
    return __builtin_amdgcn_rcpf(1.0f + e);
}
__device__ __forceinline__ float ftanh(float x) {
    float e = exp2f(x * 2.88539008f);
    return 1.0f - 2.0f * __builtin_amdgcn_rcpf(1.0f + e);
}

// W_hh fp32 [1024][256] -> bf16 fragment order:
// Wbf[((Tn*8+kc)*64+lane)*8 + j] = bf16(W_hh[16*Tn+(lane&15)][32*kc+(lane>>4)*8+j])
__global__ void wconv_kernel(const float* __restrict__ Whh,
                             unsigned short* __restrict__ Wbf) {
    int tid = blockIdx.x * blockDim.x + threadIdx.x;   // 0..32767
    int lane = tid & 63;
    int frag = tid >> 6;
    int Tn = frag >> 3;
    int kc = frag & 7;
    int n  = Tn * 16 + (lane & 15);
    int kb = kc * 32 + (lane >> 4) * 8;
    const float* src = Whh + (size_t)n * HID + kb;
    unsigned short* dst = Wbf + (size_t)tid * 8;
#pragma unroll
    for (int j = 0; j < 8; ++j) dst[j] = f2bf(src[j]);
}

#define MFMA_BF16 __builtin_amdgcn_mfma_f32_16x16x32_bf16

__global__ __launch_bounds__(THREADS, 1)
void lstm_kernel(const float* __restrict__ x,
                 const float* __restrict__ W_ih,
                 const float* __restrict__ b_ih,
                 const float* __restrict__ b_hh,
                 const float* __restrict__ W_lin,
                 const float* __restrict__ b_lin,
                 const unsigned short* __restrict__ Wbf,
                 float* __restrict__ out) {
    __shared__ __align__(16) unsigned short Wlds[16 * 8 * 64 * 8];   // 128 KB (g)
    __shared__ __align__(16) unsigned short hbuf[3][16 * HPAD];      // 25.3 KB
    __shared__ int flags[16];                                        // 64 B

    const int tid  = threadIdx.x;
    const int lane = tid & 63;
    const int w    = tid >> 6;      // wave 0..7; owns cols [32w,32w+32) = kc w
    const int l4   = lane & 15;
    const int quad = lane >> 4;
    const int r0   = blockIdx.x * 16;
    const int colA = 32 * w + l4;        // col-tile 2w
    const int colB = 32 * w + 16 + l4;   // col-tile 2w+1

    // stage g-gate tiles (Tn = 32 + 2w + ct) into LDS slots 2w+ct
#pragma unroll
    for (int ct = 0; ct < 2; ++ct)
#pragma unroll
        for (int kc = 0; kc < 8; ++kc)
            *(v4u*)(Wlds + ((size_t)(((2 * w + ct) * 8 + kc) * 64 + lane)) * 8) =
                *(const v4u*)(Wbf +
                    ((size_t)(((32 + 2 * w + ct) * 8 + kc) * 64 + lane)) * 8);

    // i,f weights register-resident, PRE-ROTATED: wif[G][ct][idx] holds
    // fragment for kc=(w+idx)&7 of tile Tn = 16*G + 2w + ct.
    v8bf wif[2][2][8];
#pragma unroll
    for (int G = 0; G < 2; ++G)
#pragma unroll
        for (int ct = 0; ct < 2; ++ct) {
            int Tn = 16 * G + 2 * w + ct;
#pragma unroll
            for (int idx = 0; idx < 8; ++idx) {
                int kc = (w + idx) & 7;
                wif[G][ct][idx] = __builtin_bit_cast(v8bf, *(const v4u*)(Wbf +
                    ((size_t)(Tn * 8 + kc) * 64 + lane) * 8));
            }
        }

    // o-gate stream bases (tiles 48+2w, 48+2w+1) + rotating quarter buffers
    const v4u* optA = (const v4u*)Wbf + ((size_t)(48 + 2 * w) * 8) * 64 + lane;
    const v4u* optB = optA + (size_t)8 * 64;
    v4u obA[4], obB[4];
#pragma unroll
    for (int j = 0; j < 4; ++j) {
        int kcj = (w + j) & 7;
        obA[j] = optA[kcj * 64];
        obB[j] = optB[kcj * 64];
    }

    // gate consts in registers
    float cw[2][4], cb[2][4];
#pragma unroll
    for (int g = 0; g < 4; ++g) {
        cw[0][g] = W_ih[g * 256 + colA];
        cb[0][g] = b_ih[g * 256 + colA] + b_hh[g * 256 + colA];
        cw[1][g] = W_ih[g * 256 + colB];
        cb[1][g] = b_ih[g * 256 + colB] + b_hh[g * 256 + colB];
    }

    // h(0)=0 in slot 0; flags=0
    for (int i = tid; i < 16 * HPAD; i += THREADS) hbuf[0][i] = 0;
    if (tid < 16) flags[tid] = 0;

    float xv[4];
#pragma unroll
    for (int r = 0; r < 4; ++r) xv[r] = x[(size_t)(r0 + quad * 4 + r) * TT];

    __syncthreads();   // only pre-loop sync

    float c_st[8];
#pragma unroll
    for (int i = 0; i < 8; ++i) c_st[i] = 0.0f;

    int cs = 0;   // t % 3
    for (int t = 0; t < TT; ++t) {
        int ns = (cs == 2) ? 0 : cs + 1;
        const unsigned short* hb = hbuf[cs] + l4 * HPAD + quad * 8;
        unsigned short* hn = hbuf[ns];

        v4f acc[2][4];
#pragma unroll
        for (int ct = 0; ct < 2; ++ct)
#pragma unroll
            for (int g = 0; g < 4; ++g) acc[ct][g] = 0.f;

#pragma unroll
        for (int idx = 0; idx < 8; ++idx) {
            int rk = (w + idx) & 7;
            if (idx != 0) {
                volatile int* vf = (volatile int*)flags;
                while (vf[rk] < t) __builtin_amdgcn_s_sleep(1);
                asm volatile("" ::: "memory");   // no hoisting reads above poll
            }
            v8bf a  = __builtin_bit_cast(v8bf, *(const v4u*)(hb + rk * 32));
            v8bf g0 = __builtin_bit_cast(v8bf, *(const v4u*)(Wlds +
                        ((size_t)(((2 * w + 0) * 8 + rk) * 64 + lane)) * 8));
            v8bf g1 = __builtin_bit_cast(v8bf, *(const v4u*)(Wlds +
                        ((size_t)(((2 * w + 1) * 8 + rk) * 64 + lane)) * 8));
            acc[0][0] = MFMA_BF16(a, wif[0][0][idx], acc[0][0], 0, 0, 0);
            acc[1][0] = MFMA_BF16(a, wif[0][1][idx], acc[1][0], 0, 0, 0);
            acc[0][1] = MFMA_BF16(a, wif[1][0][idx], acc[0][1], 0, 0, 0);
            acc[1][1] = MFMA_BF16(a, wif[1][1][idx], acc[1][1], 0, 0, 0);
            acc[0][2] = MFMA_BF16(a, g0, acc[0][2], 0, 0, 0);
            acc[1][2] = MFMA_BF16(a, g1, acc[1][2], 0, 0, 0);
            acc[0][3] = MFMA_BF16(a, __builtin_bit_cast(v8bf, obA[idx & 3]),
                                  acc[0][3], 0, 0, 0);
            acc[1][3] = MFMA_BF16(a, __builtin_bit_cast(v8bf, obB[idx & 3]),
                                  acc[1][3], 0, 0, 0);
            int pk = (w + idx + 4) & 7;   // refill slot for 4 phases ahead
            obA[idx & 3] = optA[pk * 64];
            obB[idx & 3] = optB[pk * 64];
        }

        // gates + cell update + h-write
#pragma unroll
        for (int ct = 0; ct < 2; ++ct) {
            int col = (ct == 0) ? colA : colB;
#pragma unroll
            for (int r = 0; r < 4; ++r) {
                float gi = fsigmoid(acc[ct][0][r] + xv[r] * cw[ct][0] + cb[ct][0]);
                float gf = fsigmoid(acc[ct][1][r] + xv[r] * cw[ct][1] + cb[ct][1]);
                float gg = ftanh(acc[ct][2][r] + xv[r] * cw[ct][2] + cb[ct][2]);
                float go = fsigmoid(acc[ct][3][r] + xv[r] * cw[ct][3] + cb[ct][3]);
                float cn = gf * c_st[ct * 4 + r] + gi * gg;
                c_st[ct * 4 + r] = cn;
                hn[(quad * 4 + r) * HPAD + col] = f2bf(go * ftanh(cn));
            }
        }

        // publish: drain ds writes, then epoch flag
        asm volatile("s_waitcnt lgkmcnt(0)" ::: "memory");
        if (lane == 0) *(volatile int*)&flags[w] = t + 1;

        // x prefetch for t+1 (wraps harmlessly)
        {
            int tn = (t + 1) & (TT - 1);
#pragma unroll
            for (int r = 0; r < 4; ++r)
                xv[r] = x[(size_t)(r0 + quad * 4 + r) * TT + tn];
        }
        cs = ns;
    }

    __syncthreads();

    // Epilogue: out[b] = h_final . W_lin + b_lin ; part[] aliases Wlds (dead)
    float* part = (float*)Wlds;
    {
        int rrow = tid >> 5, s5 = tid & 31;
        float p = 0.0f;
#pragma unroll
        for (int jj = 0; jj < 8; ++jj) {
            int j = s5 * 8 + jj;
            p += bf2f(hbuf[cs][rrow * HPAD + j]) * W_lin[j];
        }
        part[tid] = p;
    }
    __syncthreads();
    if (tid < 16) {
        float sum = 0.0f;
#pragma unroll
        for (int s = 0; s < 32; ++s) sum += part[tid * 32 + s];
        out[r0 + tid] = sum + b_lin[0];
    }
}

extern "C" void kernel_launch(void* const* d_in, const int* in_sizes, int n_in,
                              void* d_out, int out_size, void* d_ws, size_t ws_size,
                              hipStream_t stream) {
    const float* x     = (const float*)d_in[0];
    const float* W_ih  = (const float*)d_in[1];
    const float* W_hh  = (const float*)d_in[2];
    const float* b_ih  = (const float*)d_in[3];
    const float* b_hh  = (const float*)d_in[4];
    const float* W_lin = (const float*)d_in[5];
    const float* b_lin = (const float*)d_in[6];
    unsigned short* Wbf = (unsigned short*)d_ws;   // 512 KB

    wconv_kernel<<<128, 256, 0, stream>>>(W_hh, Wbf);
    lstm_kernel<<<NBLK, THREADS, 0, stream>>>(x, W_ih, b_ih, b_hh, W_lin, b_lin,
                                              Wbf, (float*)d_out);
}